// Round 5
// baseline (1531.687 us; speedup 1.0000x reference)
//
#include <hip/hip_runtime.h>
#include <hip/hip_bf16.h>

typedef __hip_bfloat16 bf16;

static constexpr int HN  = 4;     // heads
static constexpr int NB  = 8;     // batch
static constexpr int SEQ = 1024;  // nodes
static constexpr int EMB = 128;
static constexpr int KD  = 32;
static constexpr int FFH = 512;
static constexpr int ROWS = NB * SEQ;       // 8192
static constexpr float EPS = 1e-5f;

__device__ __forceinline__ float b2f(bf16 x){ return __bfloat162float(x); }
__device__ __forceinline__ bf16  f2b(float x){ return __float2bfloat16(x); }

// dtype-dispatched load: flag==1 -> buffer is float32, else bf16
__device__ __forceinline__ float ldx(const void* p, size_t i, int f32){
    return f32 ? ((const float*)p)[i] : b2f(((const bf16*)p)[i]);
}

// ---------------- K0: per-input dtype detector ----------------------------
// Decodes the LOW 16 bits of u32 words as bf16. Genuine bf16 data -> real
// sample (|v| < 10). f32 data -> mantissa garbage w/ random exponent -> ~1e38.
__device__ __forceinline__ float probe_max(const unsigned int* w, int nwords, int t){
    float mx = 0.f;
    for (int i = t; i < nwords; i += 256) {
        float v = fabsf(__uint_as_float(w[i] << 16));
        if (!(v <= 1e4f)) v = 1e30f;                  // NaN/inf/huge -> huge
        mx = fmaxf(mx, v);
    }
    return mx;
}

// flags: 0=input1 1=input2 2=Wq 3=Wk 4=Wv 5=Wo 6=tinyMLP(joint) 7=Wff1 8=Wff2
__global__ __launch_bounds__(256) void detect_kernel(
    const unsigned int* in1, const unsigned int* in2,
    const unsigned int* wq,  const unsigned int* wk, const unsigned int* wv,
    const unsigned int* wo,  const unsigned int* ws1, const unsigned int* bs1,
    const unsigned int* ws2, const unsigned int* bs2,
    const unsigned int* wf1, const unsigned int* wf2, int* __restrict__ flags)
{
    __shared__ float red[4];
    const int b = blockIdx.x, t = threadIdx.x;
    float mx = 0.f;
    if      (b == 0) mx = probe_max(in1, 4096, t);
    else if (b == 1) mx = probe_max(in2, 4096, t);
    else if (b == 2) mx = probe_max(wq, 4096, t);
    else if (b == 3) mx = probe_max(wk, 4096, t);
    else if (b == 4) mx = probe_max(wv, 4096, t);
    else if (b == 5) mx = probe_max(wo, 4096, t);
    else if (b == 6) {
        mx = fmaxf(probe_max(ws1, 32, t), probe_max(bs1, 4, t));
        mx = fmaxf(mx, fmaxf(probe_max(ws2, 16, t), probe_max(bs2, 2, t)));
    }
    else if (b == 7) mx = probe_max(wf1, 4096, t);
    else             mx = probe_max(wf2, 4096, t);

    #pragma unroll
    for (int off = 32; off >= 1; off >>= 1) mx = fmaxf(mx, __shfl_xor(mx, off));
    if ((t & 63) == 0) red[t >> 6] = mx;
    __syncthreads();
    if (t == 0) {
        mx = fmaxf(fmaxf(red[0], red[1]), fmaxf(red[2], red[3]));
        flags[b] = (mx > 1e4f) ? 1 : 0;
    }
}

// ---------------- K1: QKV projection --------------------------------------
// Q: [h][row][k], Kt: [h][b][k][n] (transposed for coalesced score reads), V: [h][row][k]
__global__ __launch_bounds__(256) void qkv_kernel(
    const void* __restrict__ hx, const void* __restrict__ Wq,
    const void* __restrict__ Wk, const void* __restrict__ Wv,
    bf16* __restrict__ Q, bf16* __restrict__ Kt, bf16* __restrict__ V,
    const int* __restrict__ flags)
{
    const int f_h = flags[0];
    int gid = blockIdx.x * 256 + threadIdx.x;          // 3*HN*ROWS*KD total
    int mat = gid / (HN * ROWS * KD);
    int q   = gid % (HN * ROWS * KD);
    int hh  = q / (ROWS * KD);
    int row = (q / KD) % ROWS;
    int k   = q % KD;
    const void* W = (mat == 0) ? Wq : (mat == 1) ? Wk : Wv;
    const int f_w = (mat == 0) ? flags[2] : (mat == 1) ? flags[3] : flags[4];
    size_t hbase = (size_t)row * EMB;
    size_t wbase = (size_t)hh * EMB * KD + k;
    float acc = 0.f;
    #pragma unroll 8
    for (int e = 0; e < EMB; e++) acc += ldx(hx, hbase + e, f_h) * ldx(W, wbase + (size_t)e * KD, f_w);
    bf16 r = f2b(acc);
    if (mat == 0) {
        Q[(hh * ROWS + row) * KD + k] = r;
    } else if (mat == 1) {
        int b = row >> 10, n = row & (SEQ - 1);
        Kt[((hh * NB + b) * KD + k) * SEQ + n] = r;
    } else {
        V[(hh * ROWS + row) * KD + k] = r;
    }
}

// ---------------- K2: fused attention (scores -> MLP -> softmax -> PV) ----
__global__ __launch_bounds__(256) void attn_kernel(
    const bf16* __restrict__ Q, const bf16* __restrict__ Kt, const bf16* __restrict__ V,
    const void* __restrict__ in2,
    const void* __restrict__ Ws1, const void* __restrict__ bs1,
    const void* __restrict__ Ws2, const void* __restrict__ bs2,
    float* __restrict__ heads, const int* __restrict__ flags)
{
    __shared__ float z[HN][SEQ];        // 16 KB logits
    __shared__ float qrow[HN][KD];
    __shared__ float w1[8][8], w2[8][4], bb1[8], bb2[4];
    __shared__ float invs[HN];
    __shared__ float red[256];

    const int f_2 = flags[1];
    const int f_m = flags[6];
    const int t   = threadIdx.x;
    const int row = blockIdx.x;
    const int b   = row >> 10;
    const int n   = row & (SEQ - 1);

    if (t < HN * KD) { int hh = t >> 5, k = t & 31; qrow[hh][k] = b2f(Q[(hh * ROWS + row) * KD + k]); }
    if (t >= 128 && t < 192) { int i = (t - 128) >> 3, j = t & 7; w1[i][j] = ldx(Ws1, i * 8 + j, f_m); }
    if (t >= 192 && t < 224) { int j = (t - 192) >> 2, c = t & 3; w2[j][c] = ldx(Ws2, j * 4 + c, f_m); }
    if (t >= 224 && t < 232) bb1[t - 224] = ldx(bs1, t - 224, f_m);
    if (t >= 232 && t < 236) bb2[t - 232] = ldx(bs2, t - 232, f_m);
    __syncthreads();

    // ---- scores + tiny MLP (each thread owns 4 m positions) ----
    for (int mm = t; mm < SEQ; mm += 256) {
        float x[8];
        #pragma unroll
        for (int hh = 0; hh < HN; hh++) {
            const bf16* kc = Kt + ((hh * NB + b) * KD) * SEQ + mm;
            float acc = 0.f;
            #pragma unroll
            for (int k = 0; k < KD; k++) acc += qrow[hh][k] * b2f(kc[k * SEQ]);
            x[hh] = acc;
        }
        #pragma unroll
        for (int hh = 0; hh < HN; hh++) {
            size_t idx = ((size_t)(hh * NB + b) * SEQ + n) * SEQ + mm;
            x[hh + 4] = ldx(in2, idx, f_2);
        }
        float zc[4];
        #pragma unroll
        for (int c = 0; c < 4; c++) zc[c] = bb2[c];
        #pragma unroll
        for (int j = 0; j < 8; j++) {
            float y = bb1[j];
            #pragma unroll
            for (int i = 0; i < 8; i++) y += x[i] * w1[i][j];
            y = fmaxf(y, 0.f);
            #pragma unroll
            for (int c = 0; c < 4; c++) zc[c] += y * w2[j][c];
        }
        #pragma unroll
        for (int c = 0; c < 4; c++) z[c][mm] = zc[c];
    }
    __syncthreads();

    // ---- softmax: wave w handles head w ----
    {
        int w = t >> 6, l = t & 63;
        float v[SEQ / 64];
        float mx = -1e30f;
        #pragma unroll
        for (int i = 0; i < SEQ / 64; i++) { v[i] = z[w][l + 64 * i]; mx = fmaxf(mx, v[i]); }
        #pragma unroll
        for (int off = 32; off >= 1; off >>= 1) mx = fmaxf(mx, __shfl_xor(mx, off));
        float sm = 0.f;
        #pragma unroll
        for (int i = 0; i < SEQ / 64; i++) { float e_ = __expf(v[i] - mx); z[w][l + 64 * i] = e_; sm += e_; }
        #pragma unroll
        for (int off = 32; off >= 1; off >>= 1) sm += __shfl_xor(sm, off);
        if (l == 0) invs[w] = 1.f / sm;
    }
    __syncthreads();

    // ---- PV: 128 (h,k) outputs, 2 threads each (m parity split) ----
    {
        int task = t >> 1, par = t & 1;
        int hh = task >> 5, k = task & 31;
        const bf16* vc = V + (hh * ROWS + b * SEQ) * KD + k;
        float acc = 0.f;
        #pragma unroll 4
        for (int mm = par; mm < SEQ; mm += 2) acc += z[hh][mm] * b2f(vc[mm * KD]);
        red[t] = acc;
        __syncthreads();
        if (t < 128) {
            int hh2 = t >> 5, k2 = t & 31;
            float tot = red[2 * t] + red[2 * t + 1];
            heads[(hh2 * ROWS + row) * KD + k2] = tot * invs[hh2];
        }
    }
}

// ---------------- K3: out-projection + residual + LN partials -------------
__global__ __launch_bounds__(256) void outproj_kernel(
    const float* __restrict__ heads, const void* __restrict__ Wout,
    const void* __restrict__ hx, float* __restrict__ outp,
    float* __restrict__ ps, float* __restrict__ pq, const int* __restrict__ flags)
{
    const int f_h = flags[0], f_o = flags[5];
    int gid = blockIdx.x * 256 + threadIdx.x;   // ROWS*EMB
    int row = gid >> 7, e = gid & 127;
    float acc = ldx(hx, gid, f_h);
    #pragma unroll 8
    for (int hk = 0; hk < HN * KD; hk++)
        acc += heads[((hk >> 5) * ROWS + row) * KD + (hk & 31)] * ldx(Wout, (size_t)hk * EMB + e, f_o);
    outp[gid] = acc;

    float s = acc, qq = acc * acc;
    #pragma unroll
    for (int off = 32; off >= 1; off >>= 1) { s += __shfl_xor(s, off); qq += __shfl_xor(qq, off); }
    __shared__ float ls[4], lq[4];
    int wv = threadIdx.x >> 6;
    if ((threadIdx.x & 63) == 0) { ls[wv] = s; lq[wv] = qq; }
    __syncthreads();
    if (threadIdx.x == 0) {
        ps[blockIdx.x] = ls[0] + ls[1] + ls[2] + ls[3];
        pq[blockIdx.x] = lq[0] + lq[1] + lq[2] + lq[3];
    }
}

// ---------------- K4/K7: finalize LN stats per batch ----------------------
__global__ __launch_bounds__(256) void stats_kernel(
    const float* __restrict__ ps, const float* __restrict__ pq,
    float* __restrict__ stats, int per_b, float M)
{
    int b = blockIdx.x, t = threadIdx.x;
    float s = 0.f, q = 0.f;
    for (int i = t; i < per_b; i += 256) { s += ps[b * per_b + i]; q += pq[b * per_b + i]; }
    #pragma unroll
    for (int off = 32; off >= 1; off >>= 1) { s += __shfl_xor(s, off); q += __shfl_xor(q, off); }
    __shared__ float ls[4], lq[4];
    if ((t & 63) == 0) { ls[t >> 6] = s; lq[t >> 6] = q; }
    __syncthreads();
    if (t == 0) {
        s = ls[0] + ls[1] + ls[2] + ls[3];
        q = lq[0] + lq[1] + lq[2] + lq[3];
        float mean = s / M;
        float var = (q - s * s / M) / (M - 1.0f);
        stats[2 * b] = mean;
        stats[2 * b + 1] = 1.0f / sqrtf(var + EPS);
    }
}

// ---------------- K5: apply LN (float out) --------------------------------
__global__ __launch_bounds__(256) void norm_kernel(
    const float* __restrict__ in, const float* __restrict__ stats, float* __restrict__ out)
{
    int gid = blockIdx.x * 256 + threadIdx.x;
    int b = gid >> 17;                          // 131072 per batch
    out[gid] = (in[gid] - stats[2 * b]) * stats[2 * b + 1];
}

// ---------------- K6: fused FF1+relu+FF2+residual + LN partials -----------
__global__ __launch_bounds__(256) void ff_kernel(
    const float* __restrict__ x1, const void* __restrict__ W1, const void* __restrict__ W2,
    float* __restrict__ outp, float* __restrict__ ps, float* __restrict__ pq,
    const int* __restrict__ flags)
{
    __shared__ float xr[EMB];
    __shared__ float hid[FFH];
    __shared__ float red[256];
    __shared__ float ls[2], lq[2];
    const int f_1 = flags[7], f_2 = flags[8];
    const int row = blockIdx.x, t = threadIdx.x;

    if (t < EMB) xr[t] = x1[row * EMB + t];
    __syncthreads();

    for (int f = t; f < FFH; f += 256) {
        float acc = 0.f;
        #pragma unroll 8
        for (int e = 0; e < EMB; e++) acc += xr[e] * ldx(W1, (size_t)e * FFH + f, f_1);
        hid[f] = fmaxf(acc, 0.f);
    }
    __syncthreads();

    {
        int e = t & 127, half = t >> 7;
        float acc = 0.f;
        #pragma unroll 8
        for (int f = half * 256; f < half * 256 + 256; f++) acc += hid[f] * ldx(W2, (size_t)f * EMB + e, f_2);
        red[t] = acc;
    }
    __syncthreads();

    if (t < 128) {
        float v = red[t] + red[t + 128] + xr[t];
        outp[row * EMB + t] = v;
        float s = v, q = v * v;
        #pragma unroll
        for (int off = 32; off >= 1; off >>= 1) { s += __shfl_xor(s, off); q += __shfl_xor(q, off); }
        if ((t & 63) == 0) { ls[t >> 6] = s; lq[t >> 6] = q; }
    }
    __syncthreads();
    if (t == 0) { ps[row] = ls[0] + ls[1]; pq[row] = lq[0] + lq[1]; }
}

// ---------------- K8: apply LN -> float out -------------------------------
__global__ __launch_bounds__(256) void final_kernel(
    const float* __restrict__ in, const float* __restrict__ stats, float* __restrict__ out)
{
    int gid = blockIdx.x * 256 + threadIdx.x;
    int b = gid >> 17;
    out[gid] = (in[gid] - stats[2 * b]) * stats[2 * b + 1];
}

// ---------------- K9: input2 passthrough -> float out ---------------------
// each thread handles 4 output floats
__global__ __launch_bounds__(256) void copy2_kernel(
    const void* __restrict__ in, uint4* __restrict__ out, const int* __restrict__ flags)
{
    const int f_2 = flags[1];
    size_t gid = (size_t)blockIdx.x * 256 + threadIdx.x;
    if (f_2) {
        out[gid] = ((const uint4*)in)[gid];            // raw f32x4 copy
    } else {
        const bf16* p = (const bf16*)in + gid * 4;     // bf16 -> f32 expand
        float4 v = { b2f(p[0]), b2f(p[1]), b2f(p[2]), b2f(p[3]) };
        out[gid] = *(const uint4*)&v;
    }
}

extern "C" void kernel_launch(void* const* d_in, const int* in_sizes, int n_in,
                              void* d_out, int out_size, void* d_ws, size_t ws_size,
                              hipStream_t stream)
{
    const void* input1 = d_in[0];
    const void* input2 = d_in[1];
    const void* Wq  = d_in[2];
    const void* Wk  = d_in[3];
    const void* Wv  = d_in[4];
    const void* Wo  = d_in[5];
    const void* Ws1 = d_in[6];
    const void* bs1 = d_in[7];
    const void* Ws2 = d_in[8];
    const void* bs2 = d_in[9];
    const void* Wf1 = d_in[10];
    const void* Wf2 = d_in[11];

    float* out1 = (float*)d_out;                       // [ROWS*EMB] f32
    float* out2 = (float*)d_out + (size_t)ROWS * EMB;  // input2 passthrough f32 (written LAST)

    // Scratch inside the out2 region (134 MB available, ~22 MiB used);
    // every consumer finishes before copy2 overwrites it.
    char* sb = (char*)out2;
    bf16*  Q     = (bf16*)(sb);                        // 2 MB
    bf16*  Kt    = (bf16*)(sb + (2u  << 20));          // 2 MB
    bf16*  V     = (bf16*)(sb + (4u  << 20));          // 2 MB
    float* heads = (float*)(sb + (6u  << 20));         // 4 MB
    float* outp  = (float*)(sb + (10u << 20));         // 4 MB
    float* out1n = (float*)(sb + (14u << 20));         // 4 MB
    float* outp2 = (float*)(sb + (18u << 20));         // 4 MB
    float* ps    = (float*)(sb + (22u << 20));         // 32 KB
    float* pq    = ps + 8192;                          // 32 KB
    float* stats = pq + 8192;                          // 16 floats
    float* stats2 = stats + 16;
    int*   flags = (int*)(stats2 + 16);                // 9 ints

    const float M = (float)(SEQ * EMB);                // 131072 per batch

    hipLaunchKernelGGL(detect_kernel, dim3(9), dim3(256), 0, stream,
                       (const unsigned int*)input1, (const unsigned int*)input2,
                       (const unsigned int*)Wq, (const unsigned int*)Wk,
                       (const unsigned int*)Wv, (const unsigned int*)Wo,
                       (const unsigned int*)Ws1, (const unsigned int*)bs1,
                       (const unsigned int*)Ws2, (const unsigned int*)bs2,
                       (const unsigned int*)Wf1, (const unsigned int*)Wf2, flags);
    hipLaunchKernelGGL(qkv_kernel, dim3(3 * HN * ROWS * KD / 256), dim3(256), 0, stream,
                       input1, Wq, Wk, Wv, Q, Kt, V, flags);
    hipLaunchKernelGGL(attn_kernel, dim3(ROWS), dim3(256), 0, stream,
                       Q, Kt, V, input2, Ws1, bs1, Ws2, bs2, heads, flags);
    hipLaunchKernelGGL(outproj_kernel, dim3(ROWS * EMB / 256), dim3(256), 0, stream,
                       heads, Wo, input1, outp, ps, pq, flags);
    hipLaunchKernelGGL(stats_kernel, dim3(NB), dim3(256), 0, stream,
                       ps, pq, stats, 512, M);
    hipLaunchKernelGGL(norm_kernel, dim3(ROWS * EMB / 256), dim3(256), 0, stream,
                       outp, stats, out1n);
    hipLaunchKernelGGL(ff_kernel, dim3(ROWS), dim3(256), 0, stream,
                       out1n, Wf1, Wf2, outp2, ps, pq, flags);
    hipLaunchKernelGGL(stats_kernel, dim3(NB), dim3(256), 0, stream,
                       ps, pq, stats2, 1024, M);
    hipLaunchKernelGGL(final_kernel, dim3(ROWS * EMB / 256), dim3(256), 0, stream,
                       outp2, stats2, out1);
    hipLaunchKernelGGL(copy2_kernel, dim3(ROWS * SEQ * HN / 4 / 256), dim3(256), 0, stream,
                       input2, (uint4*)out2, flags);
}